// Round 7
// baseline (202.917 us; speedup 1.0000x reference)
//
#include <hip/hip_runtime.h>

// SmallRNN: B=4096 chains, T=2048 steps, I=1, H=8, O=1, fp32.
// h_t = tanh(x_t*w_ih + W_hh h_{t-1} + b);  out = fc_w . h_T + fc_b
//
// Round 7: single-transcendental tail. R6 calibration: VALU dep level
// L ~ 4.5 cy, transcendental dep E ~ 44 cy -> exp2+rcp = ~88 of 115
// cy/step. Replace with the [7/6] Pade rational (R4-validated numerics:
//   tanh(x) ~= x(10395+1260u+21u^2)/(10395+4725u+210u^2+u^3), u=x^2,
// clamp |x|<=4.5, max err ~7e-4), hand-scheduled in asm this time:
//   - 9-term sum rebalanced to 4 chains x depth 2 -> s ready at 4L
//     (R6 was 4L for sA but 5L effective via the exp-merge fma).
//   - tail spine med3 -> u -> u2 -> den-fma -> rcp -> mul = 5L + 1E;
//     numerator (np, num) computed beside the spine, ready before rcp.
//   - non-inline constants (10395,4725,1260,210,21,4.5) preloaded in
//     VGPRs; clamp via v_med3_f32 with neg modifier (-k45).
// Path: 9L + E ~ 88 cy/step (R6: 114.7). Gathers and hazard patterns are
// R6-proven: fmac(w0,r) interlock + s_nop 0 gives 2 slots before DPP
// reads of r; m's DPP consumers sit >=3 slots after m; s_nop 1 after rcp.
//
// Layout (proven): 16 lanes/chain (8 hidden x 2 replicas; replicas make
// row_ror:4 == XOR4 and row_mirror == XOR7). 256 thr/block = 16 chains,
// grid 256 -> 1024 waves = 1 wave/SIMD on all 256 CUs. Latency-bound.

#define B_TOTAL 4096
#define T_STEPS 2048
#define H 8

__global__ __launch_bounds__(256, 1) void rnn_fused(
    const float* __restrict__ x,      // [4096, 2048]
    const float* __restrict__ w_ih,   // [8,1]
    const float* __restrict__ w_hh,   // [8,8]
    const float* __restrict__ b_ih,   // [8]
    const float* __restrict__ b_hh,   // [8]
    const float* __restrict__ fc_w,   // [1,8]
    const float* __restrict__ fc_b,   // [1]
    float* __restrict__ out)          // [4096,1]
{
    const int tid      = threadIdx.x;
    const int p        = tid & 15;          // position within 16-lane row
    const int j        = p & 7;             // hidden index (replica-agnostic)
    const int chain    = (blockIdx.x << 4) + (tid >> 4);
    const int baseLane = tid & 48;          // wave-relative base of this row

    // Plain weights: wx[N] multiplies h[j^N] (arrives via XOR-N gather).
    float wx[H];
#pragma unroll
    for (int N = 0; N < H; ++N) wx[N] = w_hh[j * H + (j ^ N)];
    const float wih = w_ih[j];
    const float bj  = b_ih[j] + b_hh[j];

    // Rational-tanh constants in VGPRs (not inline-encodable; VOP3 needs
    // register operands). Loop-invariant -> materialized once.
    const float kA = 10395.0f, kB = 4725.0f, kC = 1260.0f;
    const float kD = 210.0f,   kE = 21.0f,   k45 = 4.5f;

    const float* xp = x + (size_t)chain * T_STEPS;

    float h = 0.0f;

    // One step. Sum: 4 chains of depth 2 (m = h[j^4] via row_ror:4):
    //   c1 = (xwb + w0*h) + w1*h^1      c2 = w2*h^2 + w4*m
    //   c3 = w3*h^3 + w5*(m^1)          c4 = w7*h^7 + w6*(m^2)
    //   s  = (c1+c2) + (c3+c4)          -> 4 levels after h
    // Tail: xc=med3(s,-4.5,4.5); u=xc^2; u2=u^2;
    //   den=fma(u2, u+210, fma(u,4725,10395)); np=fma(u2,21,fma(u,1260,10395));
    //   h = (xc*np) * rcp(den)          -> 5 levels + one v_rcp
#define STEP(xval)                                                        \
    {                                                                     \
        float xwb = fmaf((xval), wih, bj);                                \
        float c1 = xwb, c2, c3, c4, m, xc, u, u2, Bq, Cq, np, den, num, rd; \
        asm volatile(                                                     \
            "v_fmac_f32 %[c1], %[w0], %[r]\n\t"                           \
            "s_nop 0\n\t"                                                 \
            "v_mov_b32_dpp %[m], %[r] row_ror:4 row_mask:0xf bank_mask:0xf\n\t" \
            "v_mul_f32_dpp %[c2], %[r], %[w2] quad_perm:[2,3,0,1] row_mask:0xf bank_mask:0xf\n\t" \
            "v_mul_f32_dpp %[c3], %[r], %[w3] quad_perm:[3,2,1,0] row_mask:0xf bank_mask:0xf\n\t" \
            "v_mul_f32_dpp %[c4], %[r], %[w7] row_mirror row_mask:0xf bank_mask:0xf\n\t" \
            "v_fmac_f32_dpp %[c1], %[r], %[w1] quad_perm:[1,0,3,2] row_mask:0xf bank_mask:0xf\n\t" \
            "v_fmac_f32 %[c2], %[w4], %[m]\n\t"                           \
            "v_fmac_f32_dpp %[c3], %[m], %[w5] quad_perm:[1,0,3,2] row_mask:0xf bank_mask:0xf\n\t" \
            "v_fmac_f32_dpp %[c4], %[m], %[w6] quad_perm:[2,3,0,1] row_mask:0xf bank_mask:0xf\n\t" \
            "v_add_f32 %[c1], %[c1], %[c2]\n\t"                           \
            "v_add_f32 %[c3], %[c3], %[c4]\n\t"                           \
            "v_add_f32 %[c1], %[c1], %[c3]\n\t"                           \
            "v_med3_f32 %[xc], %[c1], -%[k45], %[k45]\n\t"                \
            "v_mul_f32 %[u], %[xc], %[xc]\n\t"                            \
            "v_fma_f32 %[Bq], %[u], %[kB], %[kA]\n\t"                     \
            "v_mul_f32 %[u2], %[u], %[u]\n\t"                             \
            "v_add_f32 %[Cq], %[u], %[kD]\n\t"                            \
            "v_fma_f32 %[np], %[u], %[kC], %[kA]\n\t"                     \
            "v_fma_f32 %[den], %[u2], %[Cq], %[Bq]\n\t"                   \
            "v_fma_f32 %[np], %[u2], %[kE], %[np]\n\t"                    \
            "v_rcp_f32 %[rd], %[den]\n\t"                                 \
            "v_mul_f32 %[num], %[xc], %[np]\n\t"                          \
            "s_nop 0\n\t"                                                 \
            "v_mul_f32 %[r], %[num], %[rd]\n\t"                           \
            : [r] "+v"(h), [c1] "+v"(c1), [c2] "=&v"(c2), [c3] "=&v"(c3), \
              [c4] "=&v"(c4), [m] "=&v"(m), [xc] "=&v"(xc), [u] "=&v"(u), \
              [u2] "=&v"(u2), [Bq] "=&v"(Bq), [Cq] "=&v"(Cq),             \
              [np] "=&v"(np), [den] "=&v"(den), [num] "=&v"(num),         \
              [rd] "=&v"(rd)                                              \
            : [w0] "v"(wx[0]), [w1] "v"(wx[1]), [w2] "v"(wx[2]),          \
              [w3] "v"(wx[3]), [w4] "v"(wx[4]), [w5] "v"(wx[5]),          \
              [w6] "v"(wx[6]), [w7] "v"(wx[7]),                           \
              [kA] "v"(kA), [kB] "v"(kB), [kC] "v"(kC),                   \
              [kD] "v"(kD), [kE] "v"(kE), [k45] "v"(k45));                \
    }

    // 16-step unroll; prefetch the next 16 x-values a full group ahead.
    float4 c0 = *(const float4*)(xp + 0);
    float4 c1v = *(const float4*)(xp + 4);
    float4 c2v = *(const float4*)(xp + 8);
    float4 c3v = *(const float4*)(xp + 12);

    for (int t = 0; t < T_STEPS; t += 16) {
        float4 n0 = c0, n1 = c1v, n2 = c2v, n3 = c3v;
        if (t + 16 < T_STEPS) {
            n0 = *(const float4*)(xp + t + 16);
            n1 = *(const float4*)(xp + t + 20);
            n2 = *(const float4*)(xp + t + 24);
            n3 = *(const float4*)(xp + t + 28);
        }
        STEP(c0.x) STEP(c0.y) STEP(c0.z) STEP(c0.w)
        STEP(c1v.x) STEP(c1v.y) STEP(c1v.z) STEP(c1v.w)
        STEP(c2v.x) STEP(c2v.y) STEP(c2v.z) STEP(c2v.w)
        STEP(c3v.x) STEP(c3v.y) STEP(c3v.z) STEP(c3v.w)
        c0 = n0; c1v = n1; c2v = n2; c3v = n3;
    }
#undef STEP

    // Final FC (off the hot loop): gather h_T via __shfl; lane p==0 writes.
    float g[H];
#pragma unroll
    for (int k = 0; k < H; ++k) g[k] = __shfl(h, baseLane + k);
    if (p == 0) {
        float o = fc_b[0];
#pragma unroll
        for (int k = 0; k < H; ++k) o = fmaf(fc_w[k], g[k], o);
        out[chain] = o;
    }
}

extern "C" void kernel_launch(void* const* d_in, const int* in_sizes, int n_in,
                              void* d_out, int out_size, void* d_ws, size_t ws_size,
                              hipStream_t stream) {
    const float* x    = (const float*)d_in[0];
    const float* w_ih = (const float*)d_in[1];
    const float* w_hh = (const float*)d_in[2];
    const float* b_ih = (const float*)d_in[3];
    const float* b_hh = (const float*)d_in[4];
    const float* fc_w = (const float*)d_in[5];
    const float* fc_b = (const float*)d_in[6];
    float* out = (float*)d_out;

    dim3 grid(B_TOTAL / 16);   // 256 blocks -> 1 per CU
    dim3 block(256);           // 4 waves -> 1 per SIMD
    hipLaunchKernelGGL(rnn_fused, grid, block, 0, stream,
                       x, w_ih, w_hh, b_ih, b_hh, fc_w, fc_b, out);
}

// Round 8
// 171.069 us; speedup vs baseline: 1.1862x; 1.1862x over previous
//
#include <hip/hip_runtime.h>

// SmallRNN: B=4096 chains, T=2048 steps, I=1, H=8, O=1, fp32.
// h_t = tanh(x_t*w_ih + W_hh h_{t-1} + b);  out = fc_w . h_T + fc_b
//
// Round 8: R6 base (97.9us kernel, best) + Newton reciprocal.
// R6 path floor: 4L(sum) + E(exp2) + 1L(+1 fma) + E(rcp) ~ 115 cy/step
// with L~4.6, E~46. The final v_rcp is replaced by:
//   s0 = bits(0x7EF127EA - bits(d))   (~5% rel err seed)
//   s  = s0*(2 - d*s0); s = s*(2 - d*s)   (2 Newton -> ~6e-6 rel err)
// Path: 4L + E + 6L ~ 92 cy/step. +5 VALU instrs (all plain, inline-2.0,
// -d modifier; no new VGPR-resident constants -> avoids R7's register-
// shuffle tax, which cost +8 movs and +62 cy).
// Range safety: d = exp2(C*preact)+1 with |preact|<~13 -> d in [1, 3e16];
// no inf (needs C*pre>128 i.e. pre>44); seed valid over all normal d.
// r-state (R3): r = sigmoid form, h = 1-2r folded into weights.
//
// Layout (proven): 16 lanes/chain (8 hidden x 2 replicas; replicas make
// row_ror:4 == XOR4 and row_mirror == XOR7 within the 16-lane row).
// 256 thr/block = 16 chains, grid 256 -> 1024 waves = 1 wave/SIMD on all
// 256 CUs. Latency-bound: game = loop-carried dependency path.

#define B_TOTAL 4096
#define T_STEPS 2048
#define H 8

__global__ __launch_bounds__(256, 1) void rnn_fused(
    const float* __restrict__ x,      // [4096, 2048]
    const float* __restrict__ w_ih,   // [8,1]
    const float* __restrict__ w_hh,   // [8,8]
    const float* __restrict__ b_ih,   // [8]
    const float* __restrict__ b_hh,   // [8]
    const float* __restrict__ fc_w,   // [1,8]
    const float* __restrict__ fc_b,   // [1]
    float* __restrict__ out)          // [4096,1]
{
    const int tid      = threadIdx.x;
    const int p        = tid & 15;          // position within 16-lane row
    const int j        = p & 7;             // hidden index (replica-agnostic)
    const int chain    = (blockIdx.x << 4) + (tid >> 4);
    const int baseLane = tid & 48;          // wave-relative base of this row

    // C = 2*log2(e): exp(2*pre) = exp2(C*pre).
    const float C = 2.885390081777927f;

    // r-state: r = 1/(1+exp2(C*pre)), h = 1-2r folded into weights:
    //   wx[N] = -2*C*W[j][j^N],  bP = C*(b_j + rowsum W[j]),  wihC = C*wih_j
    float wx[H];
    float rowsum = 0.0f;
#pragma unroll
    for (int i = 0; i < H; ++i) rowsum += w_hh[j * H + i];
#pragma unroll
    for (int N = 0; N < H; ++N) wx[N] = -2.0f * C * w_hh[j * H + (j ^ N)];
    const float wihC = C * w_ih[j];
    const float bP   = C * (b_ih[j] + b_hh[j] + rowsum);

    const float* xp = x + (size_t)chain * T_STEPS;

    float r = 0.5f;   // h = 1 - 2r = 0

    // One step (hand-scheduled, R6-proven gathers):
    //   c1 = xwb + w0*r + w1*r^1 + w2*r^2     (3 fmacs serial)
    //   c2 = w3*r^3 + w5*(m^1)                 m = r^4 via row_ror:4
    //   c3 = w7*r^7 + w4*m + w6*(m^2)
    //   eA = exp2(c1+c2), eB = exp2(c3), d = eA*eB + 1, r = NR-rcp(d).
    // Hazards: fmac+s_nop give 2 slots before DPP reads of r; m's DPP
    // consumers sit >=3 slots after m; s_nop 1 spaces trans->VALU reads.
#define STEP(xval)                                                        \
    {                                                                     \
        float xwb = fmaf((xval), wihC, bP);                               \
        float c1 = xwb, c2, c3, m, eA, eB, d, s0, u;                      \
        asm volatile(                                                     \
            "v_fmac_f32 %[c1], %[w0], %[r]\n\t"                           \
            "s_nop 0\n\t"                                                 \
            "v_mov_b32_dpp %[m], %[r] row_ror:4 row_mask:0xf bank_mask:0xf\n\t" \
            "v_mul_f32_dpp %[c3], %[r], %[w7] row_mirror row_mask:0xf bank_mask:0xf\n\t" \
            "v_fmac_f32_dpp %[c1], %[r], %[w1] quad_perm:[1,0,3,2] row_mask:0xf bank_mask:0xf\n\t" \
            "v_mul_f32_dpp %[c2], %[r], %[w3] quad_perm:[3,2,1,0] row_mask:0xf bank_mask:0xf\n\t" \
            "v_fmac_f32 %[c3], %[w4], %[m]\n\t"                           \
            "v_fmac_f32_dpp %[c1], %[r], %[w2] quad_perm:[2,3,0,1] row_mask:0xf bank_mask:0xf\n\t" \
            "v_fmac_f32_dpp %[c2], %[m], %[w5] quad_perm:[1,0,3,2] row_mask:0xf bank_mask:0xf\n\t" \
            "v_fmac_f32_dpp %[c3], %[m], %[w6] quad_perm:[2,3,0,1] row_mask:0xf bank_mask:0xf\n\t" \
            "v_add_f32 %[c1], %[c1], %[c2]\n\t"                           \
            "v_exp_f32 %[eB], %[c3]\n\t"                                  \
            "v_exp_f32 %[eA], %[c1]\n\t"                                  \
            "s_nop 1\n\t"                                                 \
            "v_fma_f32 %[d], %[eA], %[eB], 1.0\n\t"                       \
            "v_sub_u32 %[s0], 0x7EF127EA, %[d]\n\t"                       \
            "v_fma_f32 %[u], -%[d], %[s0], 2.0\n\t"                       \
            "v_mul_f32 %[s0], %[s0], %[u]\n\t"                            \
            "v_fma_f32 %[u], -%[d], %[s0], 2.0\n\t"                       \
            "v_mul_f32 %[r], %[s0], %[u]\n\t"                             \
            : [r] "+v"(r), [c1] "+v"(c1), [c2] "=&v"(c2), [c3] "=&v"(c3), \
              [m] "=&v"(m), [eA] "=&v"(eA), [eB] "=&v"(eB),               \
              [d] "=&v"(d), [s0] "=&v"(s0), [u] "=&v"(u)                  \
            : [w0] "v"(wx[0]), [w1] "v"(wx[1]), [w2] "v"(wx[2]),          \
              [w3] "v"(wx[3]), [w4] "v"(wx[4]), [w5] "v"(wx[5]),          \
              [w6] "v"(wx[6]), [w7] "v"(wx[7]));                          \
    }

    // 16-step unroll; prefetch the next 16 x-values a full group ahead.
    // Loads + xwb fmas get scheduled between the asm blocks.
    float4 c0 = *(const float4*)(xp + 0);
    float4 c1v = *(const float4*)(xp + 4);
    float4 c2v = *(const float4*)(xp + 8);
    float4 c3v = *(const float4*)(xp + 12);

    for (int t = 0; t < T_STEPS; t += 16) {
        float4 n0 = c0, n1 = c1v, n2 = c2v, n3 = c3v;
        if (t + 16 < T_STEPS) {
            n0 = *(const float4*)(xp + t + 16);
            n1 = *(const float4*)(xp + t + 20);
            n2 = *(const float4*)(xp + t + 24);
            n3 = *(const float4*)(xp + t + 28);
        }
        STEP(c0.x) STEP(c0.y) STEP(c0.z) STEP(c0.w)
        STEP(c1v.x) STEP(c1v.y) STEP(c1v.z) STEP(c1v.w)
        STEP(c2v.x) STEP(c2v.y) STEP(c2v.z) STEP(c2v.w)
        STEP(c3v.x) STEP(c3v.y) STEP(c3v.z) STEP(c3v.w)
        c0 = n0; c1v = n1; c2v = n2; c3v = n3;
    }
#undef STEP

    // Final h from r-state; gather via __shfl (off hot loop); lane 0 writes.
    float h = fmaf(-2.0f, r, 1.0f);
    float g[H];
#pragma unroll
    for (int k = 0; k < H; ++k) g[k] = __shfl(h, baseLane + k);
    if (p == 0) {
        float o = fc_b[0];
#pragma unroll
        for (int k = 0; k < H; ++k) o = fmaf(fc_w[k], g[k], o);
        out[chain] = o;
    }
}

extern "C" void kernel_launch(void* const* d_in, const int* in_sizes, int n_in,
                              void* d_out, int out_size, void* d_ws, size_t ws_size,
                              hipStream_t stream) {
    const float* x    = (const float*)d_in[0];
    const float* w_ih = (const float*)d_in[1];
    const float* w_hh = (const float*)d_in[2];
    const float* b_ih = (const float*)d_in[3];
    const float* b_hh = (const float*)d_in[4];
    const float* fc_w = (const float*)d_in[5];
    const float* fc_b = (const float*)d_in[6];
    float* out = (float*)d_out;

    dim3 grid(B_TOTAL / 16);   // 256 blocks -> 1 per CU
    dim3 block(256);           // 4 waves -> 1 per SIMD
    hipLaunchKernelGGL(rnn_fused, grid, block, 0, stream,
                       x, w_ih, w_hh, b_ih, b_hh, fc_w, fc_b, out);
}